// Round 3
// baseline (188.497 us; speedup 1.0000x reference)
//
#include <hip/hip_runtime.h>

// ---- problem constants ----
#define B_  4
#define S_  2048
#define D_  1024
#define H_  16
#define DK_ 64
#define BH_ (B_*H_)
#define L2E 1.44269504088896f

typedef __attribute__((ext_vector_type(8))) short bf16x8;   // 8 bf16 = 4 VGPRs
typedef __attribute__((ext_vector_type(4))) float f32x4;
typedef __attribute__((ext_vector_type(16))) float f32x16;
typedef __attribute__((ext_vector_type(4))) unsigned u32x4;
typedef unsigned short u16;

__device__ __forceinline__ u16 f2bf(float f){
  unsigned u = __builtin_bit_cast(unsigned, f);
  u += 0x7fffu + ((u >> 16) & 1u);          // RNE (no NaNs in this problem)
  return (u16)(u >> 16);
}
__device__ __forceinline__ float bf2f(u16 h){
  unsigned u = ((unsigned)h) << 16;
  return __builtin_bit_cast(float, u);
}

// async global->LDS, 16B per lane; LDS dest is wave-uniform base + lane*16
#define GLD16(g,l) __builtin_amdgcn_global_load_lds( \
    (const __attribute__((address_space(1))) void*)(g), \
    (__attribute__((address_space(3))) void*)(l), 16, 0, 0)

#define MFMA16(a,b,c) __builtin_amdgcn_mfma_f32_16x16x32_bf16((a),(b),(c),0,0,0)
#define MFMA32(a,b,c) __builtin_amdgcn_mfma_f32_32x32x16_bf16((a),(b),(c),0,0,0)

#define BARR() __builtin_amdgcn_s_barrier()
#define LGKM0() do { asm volatile("s_waitcnt lgkmcnt(0)" ::: "memory"); \
                     __builtin_amdgcn_sched_barrier(0); } while(0)
#define VMW(N) asm volatile("s_waitcnt vmcnt(" #N ")" ::: "memory")

// ---------------- cast fp32 -> bf16 ----------------
__global__ void cast_kernel(const float4* __restrict__ in, ushort4* __restrict__ out, int n4){
  int i = blockIdx.x*blockDim.x + threadIdx.x;
  int stride = gridDim.x*blockDim.x;
  for (; i < n4; i += stride){
    float4 v = in[i];
    ushort4 o;
    o.x = f2bf(v.x); o.y = f2bf(v.y); o.z = f2bf(v.z); o.w = f2bf(v.w);
    out[i] = o;
  }
}

// ---------------- cast 4 weight mats (each D_*D_ fp32) in one launch -------
__global__ void cast4_kernel(const float4* __restrict__ w0, const float4* __restrict__ w1,
                             const float4* __restrict__ w2, const float4* __restrict__ w3,
                             ushort4* __restrict__ out){
  const int per = D_*D_/4;                       // 262144 float4 per matrix
  int i = blockIdx.x*blockDim.x + threadIdx.x;
  int stride = gridDim.x*blockDim.x;
  for (; i < 4*per; i += stride){
    int m = i / per, r = i - m*per;
    const float4* src = (m==0)?w0:(m==1)?w1:(m==2)?w2:w3;
    float4 v = src[r];
    ushort4 o;
    o.x = f2bf(v.x); o.y = f2bf(v.y); o.z = f2bf(v.z); o.w = f2bf(v.w);
    out[i] = o;                                   // wq,wk,wv,wo contiguous in ws
  }
}

// ---------------- RoPE cos/sin table: [S][32] ----------------
__global__ void trig_kernel(float* __restrict__ ct, float* __restrict__ st){
  int t = blockIdx.x*blockDim.x + threadIdx.x;   // S_*32 threads
  int i = t & 31, s = t >> 5;
  float expo = -(float)(2*i) * (1.0f/(float)DK_);
  float inv = powf(10000.0f, expo);
  float ang = (float)s * inv;
  ct[t] = cosf(ang);
  st[t] = sinf(ang);
}

// ============ QKV NT GEMM, 256x256 tile, 8 waves, 4-phase K-tile schedule ===
// y[i,e] = sum_d x[i,d] * W[e,d]; K=1024 fixed = 16 K-tiles of 64.
// 8 waves as 2(wm) x 4(wn); per-wave output 128x64; acc = 8x4 f32x4.
// LDS 128 KiB = 2 bufs x { gA0,gA1 (16KB each: 128 rows x 64k),
//                          gB0,gB1 (16KB each) }.
//   gA_mh = x-rows { m0+wm*128+mh*64+[0,64) : wm=0,1 }   (phase-granular)
//   gB_nh = W-rows { n0+wn*64+nh*32+[0,32)  : wn=0..3 }
// Ring schedule (per tile t, buf p=t&1, other o):
//   ph0: dsA0,dsB0 | stage[t+1,gA0]->o | bar lgkm0 mfma(0,0) bar
//   ph1: dsA1      | stage[t+1,gB1]->o | bar lgkm0 mfma(1,0) bar
//   ph2: dsB1      | stage[t+2,gB0]->p | bar lgkm0 mfma(1,1) bar
//   ph3: dsA0      | stage[t+2,gA1]->p | bar lgkm0 mfma(0,1) vmcnt(4) bar
// vmcnt(4) (=2 groups in flight) retires all of tile t+1 before it's read;
// same-buf stagings only overwrite groups whose last read was a prior phase.
// LDS XOR-swizzle: 16B-chunk c -> c^(row&7); staged via pre-swizzled SOURCE.
// z=0/1 (Q,K): LDS repack epilogue + fused RoPE (Q pre-scaled 1/8);
// z=2 (V): direct transposed stores [bh][dk][s].
__global__ __launch_bounds__(512, 2)
void gemm_qkv8(const u16* __restrict__ A,
               const u16* __restrict__ B0m, const u16* __restrict__ B1m, const u16* __restrict__ B2m,
               u16* __restrict__ O0, u16* __restrict__ O1, u16* __restrict__ O2,
               const float* __restrict__ ct, const float* __restrict__ st){
  __shared__ __align__(16) u16 lds[65536];      // 128 KiB

  // bijective XCD swizzle: 384 blocks = 8 * 48
  const int id = (int)blockIdx.x;
  const int swz = (id & 7)*48 + (id >> 3);
  const int z = swz >> 7;                        // 0,1,2
  const int rem = swz & 127;                     // 32m x 4n
  const int m0 = (rem >> 2)*256, n0 = (rem & 3)*256;

  const u16* Bm = (z==0) ? B0m : (z==1) ? B1m : B2m;
  u16* Om = (z==0) ? O0 : (z==1) ? O1 : O2;

  const int tid = threadIdx.x, wave = tid>>6, lane = tid&63;
  const int wm = wave>>2, wn = wave&3;
  const int l15 = lane & 15, l4 = lane >> 4;
  const int srow8 = lane >> 3;                       // row within 8-row GLD
  const int csw = ((lane&7) ^ srow8) << 3;           // pre-swizzled src chunk (u16)

  f32x4 acc[8][4];
  #pragma unroll
  for (int mi=0;mi<8;++mi)
    #pragma unroll
    for (int ni=0;ni<4;++ni) acc[mi][ni] = (f32x4){0.f,0.f,0.f,0.f};

  // --- staging macros: one 16KB group = 2 GLD16 per thread ---
  #define STAGE_A(pp, mh, kc) do { \
    u16* base_ = lds + (pp) + (mh)*8192; \
    _Pragma("unroll") \
    for (int j_=0;j_<2;++j_){ \
      const int lr_ = (wave*2 + j_)*8; \
      const int q_ = lr_ >> 6; \
      const size_t grow_ = (size_t)(m0 + q_*128 + (mh)*64 + (lr_ & 63) + srow8); \
      GLD16(A + grow_*1024 + (kc) + csw, base_ + lr_*64); \
    } } while(0)

  #define STAGE_B(pp, nh, kc) do { \
    u16* base_ = lds + (pp) + 16384 + (nh)*8192; \
    _Pragma("unroll") \
    for (int j_=0;j_<2;++j_){ \
      const int lr_ = (wave*2 + j_)*8; \
      const int sub_ = lr_ >> 5; \
      const size_t grow_ = (size_t)(n0 + sub_*64 + (nh)*32 + (lr_ & 31) + srow8); \
      GLD16(Bm + grow_*1024 + (kc) + csw, base_ + lr_*64); \
    } } while(0)

  bf16x8 af[4][2], bfr[2][2];
  #define LOAD_AF(pp, mh) do { \
    const u16* ab_ = lds + (pp) + (mh)*8192; \
    _Pragma("unroll") \
    for (int m_=0;m_<4;++m_) \
      _Pragma("unroll") \
      for (int kk_=0;kk_<2;++kk_){ \
        const int lr_ = wm*64 + m_*16 + l15; \
        af[m_][kk_] = *(const bf16x8*)&ab_[lr_*64 + (((kk_*4 + l4) ^ (lr_&7))<<3)]; \
      } } while(0)

  #define LOAD_BF(pp, nh) do { \
    const u16* bb_ = lds + (pp) + 16384 + (nh)*8192; \
    _Pragma("unroll") \
    for (int n_=0;n_<2;++n_) \
      _Pragma("unroll") \
      for (int kk_=0;kk_<2;++kk_){ \
        const int lr_ = wn*32 + n_*16 + l15; \
        bfr[n_][kk_] = *(const bf16x8*)&bb_[lr_*64 + (((kk_*4 + l4) ^ (lr_&7))<<3)]; \
      } } while(0)

  #define MFMAQ(mh, nh) do { \
    _Pragma("unroll") \
    for (int m_=0;m_<4;++m_) \
      _Pragma("unroll") \
      for (int n_=0;n_<2;++n_) \
        _Pragma("unroll") \
        for (int kk_=0;kk_<2;++kk_) \
          acc[(mh)*4+m_][(nh)*2+n_] = MFMA16(af[m_][kk_], bfr[n_][kk_], acc[(mh)*4+m_][(nh)*2+n_]); \
    } while(0)

  // --- prologue: tile0 all groups + tile1 {gB0, gA1}; vmcnt(4) retires tile0
  STAGE_A(0, 0, 0); STAGE_A(0, 1, 0); STAGE_B(0, 0, 0); STAGE_B(0, 1, 0);
  STAGE_B(32768, 0, 64); STAGE_A(32768, 1, 64);
  VMW(4);
  BARR();

  // --- main loop: 16 K-tiles ---
  #pragma unroll 1
  for (int t = 0; t < 16; ++t){
    const int p = (t & 1) << 15;                // u16 offset of current buf
    const int o = p ^ 32768;
    const int kc1 = ((t+1 < 16) ? t+1 : 15)*64; // clamped (tail stages garbage
    const int kc2 = ((t+2 < 16) ? t+2 : 15)*64; //  into dead regions)
    // ph0: quadrant (0,0)
    LOAD_AF(p, 0); LOAD_BF(p, 0);
    STAGE_A(o, 0, kc1);
    BARR(); LGKM0();
    __builtin_amdgcn_s_setprio(1); MFMAQ(0, 0); __builtin_amdgcn_s_setprio(0);
    BARR();
    // ph1: quadrant (1,0)
    LOAD_AF(p, 1);
    STAGE_B(o, 1, kc1);
    BARR(); LGKM0();
    __builtin_amdgcn_s_setprio(1); MFMAQ(1, 0); __builtin_amdgcn_s_setprio(0);
    BARR();
    // ph2: quadrant (1,1)
    LOAD_BF(p, 1);
    STAGE_B(p, 0, kc2);
    BARR(); LGKM0();
    __builtin_amdgcn_s_setprio(1); MFMAQ(1, 1); __builtin_amdgcn_s_setprio(0);
    BARR();
    // ph3: quadrant (0,1)
    LOAD_AF(p, 0);
    STAGE_A(p, 1, kc2);
    BARR(); LGKM0();
    __builtin_amdgcn_s_setprio(1); MFMAQ(0, 1); __builtin_amdgcn_s_setprio(0);
    VMW(4);
    BARR();
  }
  #undef STAGE_A
  #undef STAGE_B
  #undef LOAD_AF
  #undef LOAD_BF
  #undef MFMAQ

  // drain tail garbage prefetch before LDS reuse
  VMW(0);
  BARR();

  // ---- epilogue ----
  if (z != 2){
    // Q/K: repack 256x256 through LDS (XOR-swizzled), fused RoPE, 16B stores
    const float scale = (z == 0) ? 0.125f : 1.0f;
    #pragma unroll
    for (int mi=0;mi<8;++mi){
      const int rr0 = wm*128 + (mi>>2)*64 + (mi&3)*16 + l4*4;
      #pragma unroll
      for (int ni=0;ni<4;++ni){
        const int cc = wn*64 + (ni>>1)*32 + (ni&1)*16 + l15;
        #pragma unroll
        for (int r=0;r<4;++r){
          const int rr = rr0 + r;
          lds[rr*256 + (((((cc>>3) ^ (rr&7)))<<3) | (cc&7))] = f2bf(acc[mi][ni][r]);
        }
      }
    }
    __syncthreads();
    #pragma unroll
    for (int k=0;k<16;++k){
      const int cid = k*512 + tid;               // [0, 8192)
      const int rr = cid >> 5, cc8 = cid & 31;
      bf16x8 v = *(const bf16x8*)&lds[rr*256 + ((cc8 ^ (rr&7))<<3)];
      const int i = m0 + rr, bb = i >> 11, s = i & (S_-1);
      const int e0 = n0 + cc8*8, h = e0 >> 6, dk0 = e0 & 63;
      const float4 c4 = *(const float4*)(ct + s*32 + (dk0>>1));
      const float4 s4 = *(const float4*)(st + s*32 + (dk0>>1));
      const float cc4[4] = {c4.x,c4.y,c4.z,c4.w};
      const float ss4[4] = {s4.x,s4.y,s4.z,s4.w};
      bf16x8 o;
      #pragma unroll
      for (int j=0;j<4;++j){
        const float x0 = bf2f((u16)v[2*j]);
        const float x1 = bf2f((u16)v[2*j+1]);
        o[2*j]   = (short)f2bf((x0*cc4[j] - x1*ss4[j])*scale);
        o[2*j+1] = (short)f2bf((x0*ss4[j] + x1*cc4[j])*scale);
      }
      *(bf16x8*)(Om + ((size_t)((bb*H_ + h)*S_ + s))*DK_ + dk0) = o;
    }
  } else {
    // V: direct transposed stores [bh][dk][s]; 4 consecutive s per 8B store
    #pragma unroll
    for (int mi=0;mi<8;++mi){
      const int rb = m0 + wm*128 + (mi>>2)*64 + (mi&3)*16 + l4*4;
      const int b = rb >> 11, s0 = rb & (S_-1);
      #pragma unroll
      for (int ni=0;ni<4;++ni){
        const int e = n0 + wn*64 + (ni>>1)*32 + (ni&1)*16 + l15;
        const int h = e>>6, dk = e&63;
        ushort4 w4;
        w4.x = f2bf(acc[mi][ni][0]); w4.y = f2bf(acc[mi][ni][1]);
        w4.z = f2bf(acc[mi][ni][2]); w4.w = f2bf(acc[mi][ni][3]);
        *(ushort4*)(Om + ((size_t)((b*H_ + h)*DK_ + dk))*S_ + s0) = w4;
      }
    }
  }
}

// ---------------- out-projection NT GEMM (128x128, dbuf, fp32 out) ---------
__global__ __launch_bounds__(256, 2)
void gemm_out(const u16* __restrict__ A, const u16* __restrict__ Bw,
              float* __restrict__ Cf){
  __shared__ __align__(16) u16 lds[32768];

  const int id = (int)blockIdx.x;                 // 512 = 8 * 64
  const int swz = (id & 7)*64 + (id >> 3);
  const int m0 = (swz >> 3) * 128, n0 = (swz & 7) * 128;

  const int tid = threadIdx.x, wave = tid>>6, lane = tid&63;
  const int wm = wave>>1, wn = wave&1;
  const int srow = lane>>3, scol = (lane&7)*8;

  f32x4 acc[4][4];
  #pragma unroll
  for (int m=0;m<4;++m)
    #pragma unroll
    for (int n=0;n<4;++n) acc[m][n] = (f32x4){0.f,0.f,0.f,0.f};

  #define STAGE(kk0,b) { \
    u16* sA = lds + (b)*16384; \
    u16* sB = sA + 8192; \
    _Pragma("unroll") \
    for (int j=0;j<4;++j){ \
      int rb = (wave*4 + j)*8; \
      GLD16(A  + (size_t)(m0 + rb + srow)*D_ + (kk0) + scol, sA + rb*64); \
      GLD16(Bw + (size_t)(n0 + rb + srow)*D_ + (kk0) + scol, sB + rb*64); \
    } }

  STAGE(0, 0);
  __syncthreads();

  int cur = 0;
  #pragma unroll 1
  for (int k0 = 0; k0 < D_; k0 += 64){
    if (k0 + 64 < D_) STAGE(k0 + 64, cur^1);
    const u16* lA = lds + cur*16384;
    const u16* lB = lA + 8192;
    #pragma unroll
    for (int kk=0;kk<2;++kk){
      bf16x8 af[4], bfr[4];
      #pragma unroll
      for (int m=0;m<4;++m) af[m]  = *(const bf16x8*)&lA[(wm*64 + m*16 + (lane&15))*64 + kk*32 + (lane>>4)*8];
      #pragma unroll
      for (int n=0;n<4;++n) bfr[n] = *(const bf16x8*)&lB[(wn*64 + n*16 + (lane&15))*64 + kk*32 + (lane>>4)*8];
      #pragma unroll
      for (int m=0;m<4;++m)
        #pragma unroll
        for (int n=0;n<4;++n)
          acc[m][n] = MFMA16(af[m], bfr[n], acc[m][n]);
    }
    __syncthreads();
    cur ^= 1;
  }
  #undef STAGE

  #pragma unroll
  for (int m=0;m<4;++m){
    const int rb = m0 + wm*64 + m*16 + ((lane>>4)<<2);
    #pragma unroll
    for (int n=0;n<4;++n){
      const int e = n0 + wn*64 + n*16 + (lane&15);
      #pragma unroll
      for (int r=0;r<4;++r)
        Cf[(size_t)(rb + r)*D_ + e] = acc[m][n][r];
    }
  }
}

// ---------------- causal flash attention (swapped-operand, in-reg softmax) --
__global__ __launch_bounds__(256, 4)
void attn_kernel(const u16* __restrict__ Q, const u16* __restrict__ K,
                 const u16* __restrict__ Vt, u16* __restrict__ O){
  __shared__ __align__(16) u16 lK[2][64*64];
  __shared__ __align__(16) u16 lV[2][64*64];

  const int bh = blockIdx.x;
  const int qt = (int)(gridDim.y - 1 - blockIdx.y);   // heavy tiles first
  const int b = bh >> 4, h = bh & 15;
  const int tid = threadIdx.x, wave = tid>>6, lane = tid&63;
  const int hi = lane >> 5, l31 = lane & 31;
  const int q0 = qt*128, qw = q0 + wave*32;
  const int qg = qw + l31;
  const u16* Qb = Q  + (size_t)bh*S_*DK_;
  const u16* Kb = K  + (size_t)bh*S_*DK_;
  const u16* Vb = Vt + (size_t)bh*DK_*S_;

  // Q fragments (B-operand): q = lane&31 row, d-slot ds: d = ds*16 + hi*8 + e
  bf16x8 qf[4];
  #pragma unroll
  for (int ds=0; ds<4; ++ds)
    qf[ds] = *(const bf16x8*)(Qb + (size_t)qg*DK_ + ds*16 + hi*8);

  f32x16 oacc[2];
  oacc[0] = (f32x16)0.f; oacc[1] = (f32x16)0.f;
  float m_run = -1e30f, l_run = 0.f;

  const int srow8 = lane >> 3;               // staging row within 8-row group
  const int csw = ((lane&7) ^ srow8) << 3;   // pre-swizzled source chunk (u16 units)

  const int kv_end = (qt+1)*128;

  // prologue: stage tile 0 into buffer 0
  #pragma unroll
  for (int it=0; it<2; ++it){
    const int rb = (it*4 + wave)*8;
    const int row = rb + srow8;
    GLD16(Kb + (size_t)row*DK_ + csw, lK[0] + rb*64);
    GLD16(Vb + (size_t)row*S_ + csw,  lV[0] + rb*64);
  }
  __syncthreads();

  int cur = 0;
  for (int kv0 = 0; kv0 < kv_end; kv0 += 64){
    // --- issue next tile's loads into the other buffer (overlaps compute) ---
    const int nxt = kv0 + 64;
    if (nxt < kv_end){
      #pragma unroll
      for (int it=0; it<2; ++it){
        const int rb = (it*4 + wave)*8;
        const int row = rb + srow8;
        GLD16(Kb + (size_t)(nxt+row)*DK_ + csw, lK[cur^1] + rb*64);
        GLD16(Vb + (size_t)row*S_ + nxt + csw,  lV[cur^1] + rb*64);
      }
    }

    if (kv0 < qw + 32){          // wave has rows at/after this tile's start
      // --- S^T[kv][q] = K·Q^T ---
      f32x16 sacc[2];
      sacc[0] = (f32x16)0.f; sacc[1] = (f32x16)0.f;
      __builtin_amdgcn_s_setprio(1);
      #pragma unroll
      for (int kb=0; kb<2; ++kb){
        const int krow = kb*32 + l31;
        #pragma unroll
        for (int ds=0; ds<4; ++ds){
          bf16x8 kf = *(const bf16x8*)&lK[cur][krow*64 + (((ds*2+hi) ^ (krow&7))<<3)];
          sacc[kb] = MFMA32(kf, qf[ds], sacc[kb]);
        }
      }
      __builtin_amdgcn_s_setprio(0);

      // --- causal mask (diag-overlapping tiles only) ---
      if (kv0 + 63 > qw){
        #pragma unroll
        for (int kb=0; kb<2; ++kb)
          #pragma unroll
          for (int r=0; r<16; ++r){
            const int kvg = kv0 + kb*32 + 4*hi + (r&3) + 8*(r>>2);
            if (kvg > qg) sacc[kb][r] = -1e30f;
          }
      }

      // --- online softmax: all 32 vals belong to row q = lane&31 ---
      float mx = sacc[0][0];
      #pragma unroll
      for (int r=1; r<16; ++r) mx = fmaxf(mx, sacc[0][r]);
      #pragma unroll
      for (int r=0; r<16; ++r) mx = fmaxf(mx, sacc[1][r]);
      mx = fmaxf(mx, __shfl_xor(mx, 32));
      // defer-max (T13): only rescale when some row grew past 2^8 headroom
      if (!__all((mx - m_run)*L2E <= 8.0f)){
        const float mn = fmaxf(m_run, mx);
        const float alpha = exp2f((m_run - mn)*L2E);
        m_run = mn;
        l_run *= alpha;
        oacc[0] *= alpha;
        oacc[1] *= alpha;
      }
      const float nc = m_run * L2E;
      float ps = 0.f;
      #pragma unroll
      for (int kb=0; kb<2; ++kb)
        #pragma unroll
        for (int r=0; r<16; ++r){
          float v = exp2f(__builtin_fmaf(sacc[kb][r], L2E, -nc));
          sacc[kb][r] = v;
          ps += v;
        }
      ps += __shfl_xor(ps, 32);
      l_run += ps;

      // --- P -> bf16 B-frags: cvt_pk pairs + permlane32_swap (T12) ---
      bf16x8 pa[4];
      #pragma unroll
      for (int kb=0; kb<2; ++kb){
        unsigned w[8];
        #pragma unroll
        for (int i=0; i<8; ++i){
          float a = sacc[kb][2*i], b2 = sacc[kb][2*i+1];
          asm("v_cvt_pk_bf16_f32 %0, %1, %2" : "=v"(w[i]) : "v"(a), "v"(b2));
        }
        auto s02 = __builtin_amdgcn_permlane32_swap(w[0], w[2], false, false);
        auto s13 = __builtin_amdgcn_permlane32_swap(w[1], w[3], false, false);
        auto s46 = __builtin_amdgcn_permlane32_swap(w[4], w[6], false, false);
        auto s57 = __builtin_amdgcn_permlane32_swap(w[5], w[7], false, false);
        u32x4 ua = {s02[0], s13[0], s02[1], s13[1]};
        u32x4 ub = {s46[0], s57[0], s46[1], s57[1]};
        pa[kb*2+0] = __builtin_bit_cast(bf16x8, ua);
        pa[kb*2+1] = __builtin_bit_cast(bf16x8, ub);
      }

      // --- O^T[dk][q] += V^T · P ---
      __builtin_amdgcn_s_setprio(1);
      #pragma unroll
      for (int dkb=0; dkb<2; ++dkb){
        const int vrow = dkb*32 + l31;
        #pragma unroll
        for (int ks=0; ks<4; ++ks){
          bf16x8 vf = *(const bf16x8*)&lV[cur][vrow*64 + (((ks*2+hi) ^ (vrow&7))<<3)];
          oacc[dkb] = MFMA32(vf, pa[ks], oacc[dkb]);
        }
      }
      __builtin_amdgcn_s_setprio(0);
    }
    __syncthreads();   // drains this wave's prefetch loads; all buffers ready
    cur ^= 1;
  }

  // --- epilogue: lane owns output row q=qg; dk = dkb*32 + 8*(r>>2) + 4*hi + (r&3)
  const float inv = 1.0f / l_run;
  #pragma unroll
  for (int dkb=0; dkb<2; ++dkb)
    #pragma unroll
    for (int rq=0; rq<4; ++rq){
      ushort4 w4;
      w4.x = f2bf(oacc[dkb][rq*4+0]*inv);
      w4.y = f2bf(oacc[dkb][rq*4+1]*inv);
      w4.z = f2bf(oacc[dkb][rq*4+2]*inv);
      w4.w = f2bf(oacc[dkb][rq*4+3]*inv);
      const int dk0 = dkb*32 + 8*rq + 4*hi;
      *(ushort4*)(O + (size_t)(b*S_+qg)*D_ + h*DK_ + dk0) = w4;
    }
}

// ---------------- launch ----------------
extern "C" void kernel_launch(void* const* d_in, const int* in_sizes, int n_in,
                              void* d_out, int out_size, void* d_ws, size_t ws_size,
                              hipStream_t stream){
  const float* x  = (const float*)d_in[0];
  const float* Wq = (const float*)d_in[1];
  const float* Wk = (const float*)d_in[2];
  const float* Wv = (const float*)d_in[3];
  const float* Wo = (const float*)d_in[4];
  float* out = (float*)d_out;
  char* ws = (char*)d_ws;

  size_t off = 0;
  u16* xb  = (u16*)(ws + off); off += (size_t)B_*S_*D_*2;
  u16* wqb = (u16*)(ws + off); off += (size_t)D_*D_*2;
  u16* wkb = (u16*)(ws + off); off += (size_t)D_*D_*2;
  u16* wvb = (u16*)(ws + off); off += (size_t)D_*D_*2;
  u16* wob = (u16*)(ws + off); off += (size_t)D_*D_*2;
  u16* Qb  = (u16*)(ws + off); off += (size_t)BH_*S_*DK_*2;
  u16* Kb  = (u16*)(ws + off); off += (size_t)BH_*S_*DK_*2;
  u16* Vtb = (u16*)(ws + off); off += (size_t)BH_*S_*DK_*2;   // [bh][dk][s]
  u16* Ob  = (u16*)(ws + off); off += (size_t)B_*S_*D_*2;
  float* ct = (float*)(ws + off); off += (size_t)S_*32*4;
  float* st = (float*)(ws + off); off += (size_t)S_*32*4;

  cast_kernel<<<2048,256,0,stream>>>((const float4*)x,  (ushort4*)xb,  B_*S_*D_/4);
  cast4_kernel<<<1024,256,0,stream>>>((const float4*)Wq, (const float4*)Wk,
                                      (const float4*)Wv, (const float4*)Wo, (ushort4*)wqb);
  trig_kernel<<<(S_*32)/256,256,0,stream>>>(ct, st);

  // QKV projections: 256^2 tiles, 384 blocks = 32m x 4n x 3z (XCD-swizzled);
  // z=0/1 epilogue applies RoPE in-place, Q pre-scaled by 1/sqrt(DK)=0.125
  gemm_qkv8<<<384,512,0,stream>>>(xb, wqb,wkb,wvb, Qb,Kb,Vtb, ct, st);

  // causal flash attention (swapped-operand structure, double-buffered KV)
  attn_kernel<<<dim3(BH_, S_/128),256,0,stream>>>(Qb, Kb, Vtb, Ob);

  // output projection (fp32 out), flat grid 512
  gemm_out<<<512,256,0,stream>>>(Ob, wob, out);
}